// Round 9
// baseline (66.871 us; speedup 1.0000x reference)
//
#include <hip/hip_runtime.h>
#include <stdint.h>

typedef float f32x4 __attribute__((ext_vector_type(4)));

#define SDIM 7
#define NPIX 49
#define CCH 512
#define FLAT (CCH * NPIX)        // 25088 floats per tensor per batch
#define BB   (FLAT * 4)          // 100352 B per tensor per batch
#define HALF_B (BB / 2)          // 50176 B
#define NG4  (FLAT / 4)
#define NGRP (CCH / 4)
#define THRESH 0.7f
#define EPSN 1e-6f

#define SBAR() __builtin_amdgcn_sched_barrier(0)
#define WAITV(N) do { asm volatile("s_waitcnt vmcnt(" #N ")" ::: "memory"); \
                      SBAR(); } while (0)

// ============================= Kernel A ====================================
// R8 (proven correct): wave-private async DMA pipeline, counted vmcnt, no
// barriers, no masked DMA. R9 change: depth-4 -> depth-2 slots so LDS drops
// 34KB -> 17KB and EIGHT blocks fit per CU. Grid 2048 = exactly 8 blocks/CU
// -> 32 waves/CU (100% occupancy), one residency round, no turnover. The
// structure-invariant ~2.3 TB/s logical across R1-R8 ran at <=12-16 waves/CU;
// per-wave completion-rate-bound => BW should scale with resident waves.
__global__ __launch_bounds__(256) void pixpro_reduce(
    const char* __restrict__ Abytes, const char* __restrict__ Bbytes,
    float* __restrict__ partial)
{
    const int blk  = blockIdx.x;        // 0 .. 2B-1
    const int b    = blk >> 1;
    const int h    = blk & 1;
    const int tid  = threadIdx.x;
    const int lane = tid & 63;
    const int w    = tid >> 6;

    __shared__ float stage[4][2][512];  // [wave][slot][A:256f | B:256f] 16KB
    __shared__ float acc[3 * NPIX];

    if (tid < 3 * NPIX) acc[tid] = 0.f;
    __syncthreads();                    // zeros visible; nothing outstanding

    const char* srcA = Abytes + (size_t)b * BB + (size_t)h * HALF_B;
    const char* srcB = Bbytes + (size_t)b * BB + (size_t)h * HALF_B;

    const int NT = (w == 0) ? 13 : 12;  // units u = w + 4t < 49

    // stage pair t (unit u = w+4t) into slot t&1; full 64-lane 1024B copies
    #define STAGE(t) do {                                                    \
        SBAR();                                                              \
        asm volatile("s_waitcnt lgkmcnt(0)" ::: "memory");                   \
        const int u_ = w + 4 * (t);                                          \
        __builtin_amdgcn_global_load_lds(                                    \
            (const uint32_t*)(srcA + u_ * 1024 + lane * 16),                 \
            (uint32_t*)&stage[w][(t) & 1][0], 16, 0, 0);                     \
        __builtin_amdgcn_global_load_lds(                                    \
            (const uint32_t*)(srcB + u_ * 1024 + lane * 16),                 \
            (uint32_t*)&stage[w][(t) & 1][256], 16, 0, 0);                   \
        SBAR();                                                              \
    } while (0)

    float ab[4] = {0.f, 0.f, 0.f, 0.f};
    float am[4] = {0.f, 0.f, 0.f, 0.f};
    float ad[4] = {0.f, 0.f, 0.f, 0.f};
    const int q = lane;                 // pixel-column lane, q<49 active

    #define CONSUME(t) do {                                                  \
        if (q < NPIX) {                                                      \
            const int u_ = w + 4 * (t);                                      \
            int r0 = q - (15 * u_) % 49;  if (r0 < 0) r0 += 49;              \
            const f32x4* A4 = (const f32x4*)&stage[w][(t) & 1][0];           \
            const f32x4* B4 = (const f32x4*)&stage[w][(t) & 1][256];         \
            f32x4 x = A4[r0], y = B4[r0];                                    \
            _Pragma("unroll")                                                \
            for (int e = 0; e < 4; ++e) {                                    \
                ab[e] = fmaf(x[e], x[e], ab[e]);                             \
                am[e] = fmaf(y[e], y[e], am[e]);                             \
                ad[e] = fmaf(x[e], y[e], ad[e]);                             \
            }                                                                \
            if (r0 < 15) {              /* r0+49 < 64: same j-quadruple */   \
                x = A4[r0 + 49];  y = B4[r0 + 49];                           \
                _Pragma("unroll")                                            \
                for (int e = 0; e < 4; ++e) {                                \
                    ab[e] = fmaf(x[e], x[e], ab[e]);                         \
                    am[e] = fmaf(y[e], y[e], am[e]);                         \
                    ad[e] = fmaf(x[e], y[e], ad[e]);                         \
                }                                                            \
            }                                                                \
        }                                                                    \
    } while (0)

    // ---- wave-local pipeline: 2 pairs (4 DMAs) in flight, counted waits ---
    STAGE(0);  STAGE(1);                     // outstanding = 4
    for (int t = 0; t < NT - 2; ++t) {
        WAITV(2);                            // pair t landed (oldest 2)
        CONSUME(t);
        STAGE(t + 2);                        // back to 4 outstanding
    }
    WAITV(2);  CONSUME(NT - 2);
    WAITV(0);  CONSUME(NT - 1);

    #undef STAGE
    #undef CONSUME

    // ---- merge: all DMA retired; LDS atomics, then block barrier ----
    if (q < NPIX) {
        #pragma unroll
        for (int e = 0; e < 4; ++e) {
            const int j = (4 * q + e) % NPIX;      // static per (q,e)
            atomicAdd(&acc[j],            ab[e]);
            atomicAdd(&acc[NPIX + j],     am[e]);
            atomicAdd(&acc[2 * NPIX + j], ad[e]);
        }
    }
    __syncthreads();

    if (tid < 3 * NPIX)
        partial[(size_t)blk * (3 * NPIX) + tid] = acc[tid];
}

// ============================= Kernel B ====================================
// One 64-thread block per batch b: merge the 2 half-batch partials -> cos[j];
// warp grids; 49x49 pair loop; write (contrib, interFlag) to slot b.
__global__ __launch_bounds__(64) void pixpro_pairs(
    const float* __restrict__ partial,
    const float* __restrict__ pb, const float* __restrict__ pm,
    const int* __restrict__ fb, const int* __restrict__ fm,
    float* __restrict__ perb)
{
    const int b   = blockIdx.x;
    const int tid = threadIdx.x;

    __shared__ float cosj[NPIX];
    __shared__ float gbx[NPIX], gby[NPIX], gmx[NPIX], gmy[NPIX];

    const float xb = pb[b * 4 + 0], yb = pb[b * 4 + 1];
    const float wb = pb[b * 4 + 2], hb = pb[b * 4 + 3];
    const float xm = pm[b * 4 + 0], ym = pm[b * 4 + 1];
    const float wm = pm[b * 4 + 2], hm = pm[b * 4 + 3];
    const bool flb = (fb[b] != 0);
    const bool flm = (fm[b] != 0);

    if (tid < NPIX) {
        float sqb = 0.f, sqm = 0.f, dt = 0.f;
        #pragma unroll
        for (int c = 0; c < 2; ++c) {
            const float* p = partial + (size_t)(2 * b + c) * (3 * NPIX);
            sqb += p[tid];
            sqm += p[NPIX + tid];
            dt  += p[2 * NPIX + tid];
        }
        const float nb = fmaxf(sqrtf(sqb), EPSN);
        const float nm = fmaxf(sqrtf(sqm), EPSN);
        cosj[tid] = dt / (nb * nm);

        // grid: n = i*7 + jj ; g[i][jj] = (gx[i], gy[flip ? 6-jj : jj])
        const int i  = tid / SDIM;
        const int jj = tid % SDIM;
        const float ti = (float)i * (1.0f / 6.0f);
        const int jb = flb ? (6 - jj) : jj;
        const int jm = flm ? (6 - jj) : jj;
        gbx[tid] = xb + wb * ti;
        gby[tid] = yb + hb * ((float)jb * (1.0f / 6.0f));
        gmx[tid] = xm + wm * ti;
        gmy[tid] = ym + hm * ((float)jm * (1.0f / 6.0f));
    }
    __syncthreads();

    // A_b[i][j]: dist(gb[i],gm[j]) < 0.7*diag_b -> s_b += cos[j]
    // A_m (after swapaxes): dist(gb[i],gm[j]) < 0.7*diag_m -> s_m += cos[i]
    const float thrb2 = THRESH * THRESH * (wb * wb + hb * hb);
    const float thrm2 = THRESH * THRESH * (wm * wm + hm * hm);
    float sb = 0.f, sm = 0.f;
    int nnzb = 0, nnzm = 0;
    for (int p = tid; p < NPIX * NPIX; p += 64) {
        const int i = p / NPIX;
        const int j = p - i * NPIX;
        const float dx = gbx[i] - gmx[j];
        const float dy = gby[i] - gmy[j];
        const float d2 = dx * dx + dy * dy;
        if (d2 < thrb2) { ++nnzb; sb += cosj[j]; }
        if (d2 < thrm2) { ++nnzm; sm += cosj[i]; }
    }
    #pragma unroll
    for (int off = 32; off; off >>= 1) {
        sb   += __shfl_down(sb, off);
        sm   += __shfl_down(sm, off);
        nnzb += __shfl_down(nnzb, off);
        nnzm += __shfl_down(nnzm, off);
    }
    if (tid == 0) {
        const float lossb = (nnzb > 0) ? sb / (float)nnzb : 0.f;
        const float lossm = (nnzm > 0) ? sm / (float)nnzm : 0.f;
        const float cx1 = xb + 0.5f * wb, cx2 = xm + 0.5f * wm;
        const float cy1 = yb + 0.5f * hb, cy2 = ym + 0.5f * hm;
        const bool inter = (fabsf(cx1 - cx2) * 2.f < wb + wm) &&
                           (fabsf(cy1 - cy2) * 2.f < hb + hm);
        perb[b * 2 + 0] = inter ? -(lossb + lossm) : 0.f;
        perb[b * 2 + 1] = inter ? 1.f : 0.f;
    }
}

// ============================= Kernel C ====================================
__global__ __launch_bounds__(1024) void pixpro_final(
    const float* __restrict__ perb, float* __restrict__ out, int B)
{
    const int tid = threadIdx.x;
    float c = 0.f, n = 0.f;
    for (int i = tid; i < B; i += 1024) {
        c += perb[2 * i + 0];
        n += perb[2 * i + 1];
    }
    #pragma unroll
    for (int off = 32; off; off >>= 1) {
        c += __shfl_down(c, off);
        n += __shfl_down(n, off);
    }
    __shared__ float red[32];
    const int wid = tid >> 6;
    if ((tid & 63) == 0) { red[wid * 2] = c; red[wid * 2 + 1] = n; }
    __syncthreads();
    if (tid == 0) {
        float C = 0.f, N = 0.f;
        for (int w = 0; w < 16; ++w) { C += red[w * 2]; N += red[w * 2 + 1]; }
        out[0] = C / fmaxf(N, 1.0f);
    }
}

// ===================== Fallback mono kernel (small ws) =====================
__global__ __launch_bounds__(256) void pixpro_mono(
    const float4* __restrict__ base4, const float4* __restrict__ moment4,
    const float* __restrict__ pb, const float* __restrict__ pm,
    const int* __restrict__ fb, const int* __restrict__ fm,
    float* __restrict__ accum)
{
    const int b   = blockIdx.x;
    const int tid = threadIdx.x;
    __shared__ float lds_sqb[NPIX], lds_sqm[NPIX], lds_dot[NPIX];
    __shared__ float cosj[NPIX], gbx[NPIX], gby[NPIX], gmx[NPIX], gmy[NPIX];
    __shared__ float red[16];
    if (tid < NPIX) { lds_sqb[tid]=0.f; lds_sqm[tid]=0.f; lds_dot[tid]=0.f; }
    const float xb = pb[b*4+0], yb = pb[b*4+1], wb = pb[b*4+2], hb = pb[b*4+3];
    const float xm = pm[b*4+0], ym = pm[b*4+1], wm = pm[b*4+2], hm = pm[b*4+3];
    const bool flb = (fb[b] != 0), flm = (fm[b] != 0);
    float accb[4]={0,0,0,0}, accm[4]={0,0,0,0}, accd[4]={0,0,0,0};
    if (tid < 5 * NPIX) {
        const int q = tid % NPIX, gl = tid / NPIX;
        const float4* bp = base4   + (size_t)b * NG4 + q;
        const float4* mp = moment4 + (size_t)b * NG4 + q;
        for (int g = gl; g < NGRP; g += 5) {
            const float4 x = bp[(size_t)g * NPIX];
            const float4 y = mp[(size_t)g * NPIX];
            accb[0]=fmaf(x.x,x.x,accb[0]); accm[0]=fmaf(y.x,y.x,accm[0]); accd[0]=fmaf(x.x,y.x,accd[0]);
            accb[1]=fmaf(x.y,x.y,accb[1]); accm[1]=fmaf(y.y,y.y,accm[1]); accd[1]=fmaf(x.y,y.y,accd[1]);
            accb[2]=fmaf(x.z,x.z,accb[2]); accm[2]=fmaf(y.z,y.z,accm[2]); accd[2]=fmaf(x.z,y.z,accd[2]);
            accb[3]=fmaf(x.w,x.w,accb[3]); accm[3]=fmaf(y.w,y.w,accm[3]); accd[3]=fmaf(x.w,y.w,accd[3]);
        }
    }
    __syncthreads();
    if (tid < 5 * NPIX) {
        const int q = tid % NPIX;
        #pragma unroll
        for (int e = 0; e < 4; ++e) {
            const int j = (4 * q + e) % NPIX;
            atomicAdd(&lds_sqb[j], accb[e]);
            atomicAdd(&lds_sqm[j], accm[e]);
            atomicAdd(&lds_dot[j], accd[e]);
        }
    }
    __syncthreads();
    if (tid < NPIX) {
        float nb = fmaxf(sqrtf(lds_sqb[tid]), EPSN);
        float nm = fmaxf(sqrtf(lds_sqm[tid]), EPSN);
        cosj[tid] = lds_dot[tid] / (nb * nm);
        const int i = tid / SDIM, jj = tid % SDIM;
        const float ti = (float)i * (1.0f/6.0f);
        const int jb = flb ? (6-jj) : jj, jm = flm ? (6-jj) : jj;
        gbx[tid] = xb + wb * ti;
        gby[tid] = yb + hb * ((float)jb * (1.0f/6.0f));
        gmx[tid] = xm + wm * ti;
        gmy[tid] = ym + hm * ((float)jm * (1.0f/6.0f));
    }
    __syncthreads();
    const float thrb2 = THRESH*THRESH*(wb*wb+hb*hb);
    const float thrm2 = THRESH*THRESH*(wm*wm+hm*hm);
    float sb = 0.f, sm = 0.f; int nnzb = 0, nnzm = 0;
    for (int p = tid; p < NPIX*NPIX; p += 256) {
        const int i = p / NPIX, j = p - i*NPIX;
        const float dx = gbx[i]-gmx[j], dy = gby[i]-gmy[j];
        const float d2 = dx*dx + dy*dy;
        if (d2 < thrb2) { ++nnzb; sb += cosj[j]; }
        if (d2 < thrm2) { ++nnzm; sm += cosj[i]; }
    }
    for (int off = 32; off; off >>= 1) {
        sb += __shfl_down(sb,off); sm += __shfl_down(sm,off);
        nnzb += __shfl_down(nnzb,off); nnzm += __shfl_down(nnzm,off);
    }
    const int wid = tid >> 6;
    if ((tid & 63) == 0) {
        red[wid*4+0]=sb; red[wid*4+1]=sm; red[wid*4+2]=(float)nnzb; red[wid*4+3]=(float)nnzm;
    }
    __syncthreads();
    if (tid == 0) {
        float SB=0,SM=0,NB=0,NM=0;
        for (int w=0;w<4;++w){SB+=red[w*4+0];SM+=red[w*4+1];NB+=red[w*4+2];NM+=red[w*4+3];}
        const float lossb = (NB>0.f)?SB/NB:0.f, lossm = (NM>0.f)?SM/NM:0.f;
        const float cx1=xb+0.5f*wb, cx2=xm+0.5f*wm, cy1=yb+0.5f*hb, cy2=ym+0.5f*hm;
        const bool inter = (fabsf(cx1-cx2)*2.f < wb+wm) && (fabsf(cy1-cy2)*2.f < hb+hm);
        if (inter) { atomicAdd(&accum[0], -(lossb+lossm)); atomicAdd(&accum[1], 1.f); }
    }
}

__global__ void pixpro_mono_final(const float* __restrict__ accum,
                                  float* __restrict__ out)
{
    out[0] = accum[0] / fmaxf(accum[1], 1.0f);
}

// ============================= launch ======================================
extern "C" void kernel_launch(void* const* d_in, const int* in_sizes, int n_in,
                              void* d_out, int out_size, void* d_ws, size_t ws_size,
                              hipStream_t stream)
{
    const float* pbase = (const float*)d_in[2];
    const float* pmom  = (const float*)d_in[3];
    const int*   fbase = (const int*)d_in[4];
    const int*   fmom  = (const int*)d_in[5];
    float* out = (float*)d_out;

    const int B = in_sizes[2] / 4;   // p_base is (B,4)

    const size_t need = (size_t)B * 2 * (3 * NPIX) * sizeof(float)
                      + (size_t)B * 2 * sizeof(float);
    if (ws_size >= need) {
        const char* Ab = (const char*)d_in[0];
        const char* Bb = (const char*)d_in[1];
        float* partial = (float*)d_ws;
        float* perb    = partial + (size_t)B * 2 * (3 * NPIX);
        pixpro_reduce<<<B * 2, 256, 0, stream>>>(Ab, Bb, partial);
        pixpro_pairs<<<B, 64, 0, stream>>>(partial, pbase, pmom, fbase, fmom, perb);
        pixpro_final<<<1, 1024, 0, stream>>>(perb, out, B);
    } else {
        const float4* base4   = (const float4*)d_in[0];
        const float4* moment4 = (const float4*)d_in[1];
        float* accum = (float*)d_ws;  // 2 floats
        hipMemsetAsync(accum, 0, 2 * sizeof(float), stream);
        pixpro_mono<<<B, 256, 0, stream>>>(base4, moment4, pbase, pmom, fbase, fmom, accum);
        pixpro_mono_final<<<1, 1, 0, stream>>>(accum, out);
    }
}

// Round 10
// 65.951 us; speedup vs baseline: 1.0140x; 1.0140x over previous
//
#include <hip/hip_runtime.h>
#include <stdint.h>

typedef float f32x4 __attribute__((ext_vector_type(4)));

#define SDIM 7
#define NPIX 49
#define CCH 512
#define FLAT (CCH * NPIX)        // 25088 floats per tensor per batch
#define BB   (FLAT * 4)          // 100352 B per tensor per batch
#define HALF_B (BB / 2)          // 50176 B
#define NG4  (FLAT / 4)
#define NGRP (CCH / 4)
#define THRESH 0.7f
#define EPSN 1e-6f

// cache policy for global_load_lds aux: gfx94x/gfx950 CPol NT bit
#define AUX_NT 2

#define SBAR() __builtin_amdgcn_sched_barrier(0)
#define WAITV(N) do { asm volatile("s_waitcnt vmcnt(" #N ")" ::: "memory"); \
                      SBAR(); } while (0)

// ============================= Kernel A ====================================
// R8 structure (proven correct, best at 66.1us): wave-private async DMA
// pipeline, depth-4 slots, 3 pairs (6 DMAs) in flight, counted vmcnt, no
// barriers in loop, no masked DMA. R10 probe: NT (non-temporal) cache policy
// on the DMA reads. R1-R9 invariant: logical read rate pinned at ~3.3 TB/s
// across all structures == per-CU MSHR x latency cap (matches m13 copy's
// ~3.15 TB/s read side). NT changes the L3/HBM latency mix -> if time is
// unchanged, the cap is real and we are at the streaming-read roofline.
__global__ __launch_bounds__(256) void pixpro_reduce(
    const char* __restrict__ Abytes, const char* __restrict__ Bbytes,
    float* __restrict__ partial)
{
    const int blk  = blockIdx.x;        // 0 .. 2B-1
    const int b    = blk >> 1;
    const int h    = blk & 1;
    const int tid  = threadIdx.x;
    const int lane = tid & 63;
    const int w    = tid >> 6;

    __shared__ float stage[4][4][512];  // [wave][slot][A:256f | B:256f] 32KB
    __shared__ float acc[3 * NPIX];

    if (tid < 3 * NPIX) acc[tid] = 0.f;
    __syncthreads();                    // zeros visible; nothing outstanding

    const char* srcA = Abytes + (size_t)b * BB + (size_t)h * HALF_B;
    const char* srcB = Bbytes + (size_t)b * BB + (size_t)h * HALF_B;

    const int NT = (w == 0) ? 13 : 12;  // units u = w + 4t < 49

    // stage pair t (unit u = w+4t) into slot t&3; full 64-lane 1024B copies
    #define STAGE(t) do {                                                    \
        SBAR();                                                              \
        asm volatile("s_waitcnt lgkmcnt(0)" ::: "memory");                   \
        const int u_ = w + 4 * (t);                                          \
        __builtin_amdgcn_global_load_lds(                                    \
            (const uint32_t*)(srcA + u_ * 1024 + lane * 16),                 \
            (uint32_t*)&stage[w][(t) & 3][0], 16, 0, AUX_NT);                \
        __builtin_amdgcn_global_load_lds(                                    \
            (const uint32_t*)(srcB + u_ * 1024 + lane * 16),                 \
            (uint32_t*)&stage[w][(t) & 3][256], 16, 0, AUX_NT);              \
        SBAR();                                                              \
    } while (0)

    float ab[4] = {0.f, 0.f, 0.f, 0.f};
    float am[4] = {0.f, 0.f, 0.f, 0.f};
    float ad[4] = {0.f, 0.f, 0.f, 0.f};
    const int q = lane;                 // pixel-column lane, q<49 active

    #define CONSUME(t) do {                                                  \
        if (q < NPIX) {                                                      \
            const int u_ = w + 4 * (t);                                      \
            int r0 = q - (15 * u_) % 49;  if (r0 < 0) r0 += 49;              \
            const f32x4* A4 = (const f32x4*)&stage[w][(t) & 3][0];           \
            const f32x4* B4 = (const f32x4*)&stage[w][(t) & 3][256];         \
            f32x4 x = A4[r0], y = B4[r0];                                    \
            _Pragma("unroll")                                                \
            for (int e = 0; e < 4; ++e) {                                    \
                ab[e] = fmaf(x[e], x[e], ab[e]);                             \
                am[e] = fmaf(y[e], y[e], am[e]);                             \
                ad[e] = fmaf(x[e], y[e], ad[e]);                             \
            }                                                                \
            if (r0 < 15) {              /* r0+49 < 64: same j-quadruple */   \
                x = A4[r0 + 49];  y = B4[r0 + 49];                           \
                _Pragma("unroll")                                            \
                for (int e = 0; e < 4; ++e) {                                \
                    ab[e] = fmaf(x[e], x[e], ab[e]);                         \
                    am[e] = fmaf(y[e], y[e], am[e]);                         \
                    ad[e] = fmaf(x[e], y[e], ad[e]);                         \
                }                                                            \
            }                                                                \
        }                                                                    \
    } while (0)

    // ---- wave-local pipeline: 3 pairs (6 DMAs) in flight, counted waits ---
    STAGE(0);  STAGE(1);  STAGE(2);          // outstanding = 6
    for (int t = 0; t < NT - 3; ++t) {
        WAITV(4);                            // pair t landed (oldest 2)
        CONSUME(t);
        STAGE(t + 3);                        // back to 6 outstanding
    }
    WAITV(4);  CONSUME(NT - 3);
    WAITV(2);  CONSUME(NT - 2);
    WAITV(0);  CONSUME(NT - 1);

    #undef STAGE
    #undef CONSUME

    // ---- merge: all DMA retired; LDS atomics, then block barrier ----
    if (q < NPIX) {
        #pragma unroll
        for (int e = 0; e < 4; ++e) {
            const int j = (4 * q + e) % NPIX;      // static per (q,e)
            atomicAdd(&acc[j],            ab[e]);
            atomicAdd(&acc[NPIX + j],     am[e]);
            atomicAdd(&acc[2 * NPIX + j], ad[e]);
        }
    }
    __syncthreads();

    if (tid < 3 * NPIX)
        partial[(size_t)blk * (3 * NPIX) + tid] = acc[tid];
}

// ============================= Kernel B ====================================
// One 64-thread block per batch b: merge the 2 half-batch partials -> cos[j];
// warp grids; 49x49 pair loop; write (contrib, interFlag) to slot b.
__global__ __launch_bounds__(64) void pixpro_pairs(
    const float* __restrict__ partial,
    const float* __restrict__ pb, const float* __restrict__ pm,
    const int* __restrict__ fb, const int* __restrict__ fm,
    float* __restrict__ perb)
{
    const int b   = blockIdx.x;
    const int tid = threadIdx.x;

    __shared__ float cosj[NPIX];
    __shared__ float gbx[NPIX], gby[NPIX], gmx[NPIX], gmy[NPIX];

    const float xb = pb[b * 4 + 0], yb = pb[b * 4 + 1];
    const float wb = pb[b * 4 + 2], hb = pb[b * 4 + 3];
    const float xm = pm[b * 4 + 0], ym = pm[b * 4 + 1];
    const float wm = pm[b * 4 + 2], hm = pm[b * 4 + 3];
    const bool flb = (fb[b] != 0);
    const bool flm = (fm[b] != 0);

    if (tid < NPIX) {
        float sqb = 0.f, sqm = 0.f, dt = 0.f;
        #pragma unroll
        for (int c = 0; c < 2; ++c) {
            const float* p = partial + (size_t)(2 * b + c) * (3 * NPIX);
            sqb += p[tid];
            sqm += p[NPIX + tid];
            dt  += p[2 * NPIX + tid];
        }
        const float nb = fmaxf(sqrtf(sqb), EPSN);
        const float nm = fmaxf(sqrtf(sqm), EPSN);
        cosj[tid] = dt / (nb * nm);

        // grid: n = i*7 + jj ; g[i][jj] = (gx[i], gy[flip ? 6-jj : jj])
        const int i  = tid / SDIM;
        const int jj = tid % SDIM;
        const float ti = (float)i * (1.0f / 6.0f);
        const int jb = flb ? (6 - jj) : jj;
        const int jm = flm ? (6 - jj) : jj;
        gbx[tid] = xb + wb * ti;
        gby[tid] = yb + hb * ((float)jb * (1.0f / 6.0f));
        gmx[tid] = xm + wm * ti;
        gmy[tid] = ym + hm * ((float)jm * (1.0f / 6.0f));
    }
    __syncthreads();

    // A_b[i][j]: dist(gb[i],gm[j]) < 0.7*diag_b -> s_b += cos[j]
    // A_m (after swapaxes): dist(gb[i],gm[j]) < 0.7*diag_m -> s_m += cos[i]
    const float thrb2 = THRESH * THRESH * (wb * wb + hb * hb);
    const float thrm2 = THRESH * THRESH * (wm * wm + hm * hm);
    float sb = 0.f, sm = 0.f;
    int nnzb = 0, nnzm = 0;
    for (int p = tid; p < NPIX * NPIX; p += 64) {
        const int i = p / NPIX;
        const int j = p - i * NPIX;
        const float dx = gbx[i] - gmx[j];
        const float dy = gby[i] - gmy[j];
        const float d2 = dx * dx + dy * dy;
        if (d2 < thrb2) { ++nnzb; sb += cosj[j]; }
        if (d2 < thrm2) { ++nnzm; sm += cosj[i]; }
    }
    #pragma unroll
    for (int off = 32; off; off >>= 1) {
        sb   += __shfl_down(sb, off);
        sm   += __shfl_down(sm, off);
        nnzb += __shfl_down(nnzb, off);
        nnzm += __shfl_down(nnzm, off);
    }
    if (tid == 0) {
        const float lossb = (nnzb > 0) ? sb / (float)nnzb : 0.f;
        const float lossm = (nnzm > 0) ? sm / (float)nnzm : 0.f;
        const float cx1 = xb + 0.5f * wb, cx2 = xm + 0.5f * wm;
        const float cy1 = yb + 0.5f * hb, cy2 = ym + 0.5f * hm;
        const bool inter = (fabsf(cx1 - cx2) * 2.f < wb + wm) &&
                           (fabsf(cy1 - cy2) * 2.f < hb + hm);
        perb[b * 2 + 0] = inter ? -(lossb + lossm) : 0.f;
        perb[b * 2 + 1] = inter ? 1.f : 0.f;
    }
}

// ============================= Kernel C ====================================
__global__ __launch_bounds__(1024) void pixpro_final(
    const float* __restrict__ perb, float* __restrict__ out, int B)
{
    const int tid = threadIdx.x;
    float c = 0.f, n = 0.f;
    for (int i = tid; i < B; i += 1024) {
        c += perb[2 * i + 0];
        n += perb[2 * i + 1];
    }
    #pragma unroll
    for (int off = 32; off; off >>= 1) {
        c += __shfl_down(c, off);
        n += __shfl_down(n, off);
    }
    __shared__ float red[32];
    const int wid = tid >> 6;
    if ((tid & 63) == 0) { red[wid * 2] = c; red[wid * 2 + 1] = n; }
    __syncthreads();
    if (tid == 0) {
        float C = 0.f, N = 0.f;
        for (int w = 0; w < 16; ++w) { C += red[w * 2]; N += red[w * 2 + 1]; }
        out[0] = C / fmaxf(N, 1.0f);
    }
}

// ===================== Fallback mono kernel (small ws) =====================
__global__ __launch_bounds__(256) void pixpro_mono(
    const float4* __restrict__ base4, const float4* __restrict__ moment4,
    const float* __restrict__ pb, const float* __restrict__ pm,
    const int* __restrict__ fb, const int* __restrict__ fm,
    float* __restrict__ accum)
{
    const int b   = blockIdx.x;
    const int tid = threadIdx.x;
    __shared__ float lds_sqb[NPIX], lds_sqm[NPIX], lds_dot[NPIX];
    __shared__ float cosj[NPIX], gbx[NPIX], gby[NPIX], gmx[NPIX], gmy[NPIX];
    __shared__ float red[16];
    if (tid < NPIX) { lds_sqb[tid]=0.f; lds_sqm[tid]=0.f; lds_dot[tid]=0.f; }
    const float xb = pb[b*4+0], yb = pb[b*4+1], wb = pb[b*4+2], hb = pb[b*4+3];
    const float xm = pm[b*4+0], ym = pm[b*4+1], wm = pm[b*4+2], hm = pm[b*4+3];
    const bool flb = (fb[b] != 0), flm = (fm[b] != 0);
    float accb[4]={0,0,0,0}, accm[4]={0,0,0,0}, accd[4]={0,0,0,0};
    if (tid < 5 * NPIX) {
        const int q = tid % NPIX, gl = tid / NPIX;
        const float4* bp = base4   + (size_t)b * NG4 + q;
        const float4* mp = moment4 + (size_t)b * NG4 + q;
        for (int g = gl; g < NGRP; g += 5) {
            const float4 x = bp[(size_t)g * NPIX];
            const float4 y = mp[(size_t)g * NPIX];
            accb[0]=fmaf(x.x,x.x,accb[0]); accm[0]=fmaf(y.x,y.x,accm[0]); accd[0]=fmaf(x.x,y.x,accd[0]);
            accb[1]=fmaf(x.y,x.y,accb[1]); accm[1]=fmaf(y.y,y.y,accm[1]); accd[1]=fmaf(x.y,y.y,accd[1]);
            accb[2]=fmaf(x.z,x.z,accb[2]); accm[2]=fmaf(y.z,y.z,accm[2]); accd[2]=fmaf(x.z,y.z,accd[2]);
            accb[3]=fmaf(x.w,x.w,accb[3]); accm[3]=fmaf(y.w,y.w,accm[3]); accd[3]=fmaf(x.w,y.w,accd[3]);
        }
    }
    __syncthreads();
    if (tid < 5 * NPIX) {
        const int q = tid % NPIX;
        #pragma unroll
        for (int e = 0; e < 4; ++e) {
            const int j = (4 * q + e) % NPIX;
            atomicAdd(&lds_sqb[j], accb[e]);
            atomicAdd(&lds_sqm[j], accm[e]);
            atomicAdd(&lds_dot[j], accd[e]);
        }
    }
    __syncthreads();
    if (tid < NPIX) {
        float nb = fmaxf(sqrtf(lds_sqb[tid]), EPSN);
        float nm = fmaxf(sqrtf(lds_sqm[tid]), EPSN);
        cosj[tid] = lds_dot[tid] / (nb * nm);
        const int i = tid / SDIM, jj = tid % SDIM;
        const float ti = (float)i * (1.0f/6.0f);
        const int jb = flb ? (6-jj) : jj, jm = flm ? (6-jj) : jj;
        gbx[tid] = xb + wb * ti;
        gby[tid] = yb + hb * ((float)jb * (1.0f/6.0f));
        gmx[tid] = xm + wm * ti;
        gmy[tid] = ym + hm * ((float)jm * (1.0f/6.0f));
    }
    __syncthreads();
    const float thrb2 = THRESH*THRESH*(wb*wb+hb*hb);
    const float thrm2 = THRESH*THRESH*(wm*wm+hm*hm);
    float sb = 0.f, sm = 0.f; int nnzb = 0, nnzm = 0;
    for (int p = tid; p < NPIX*NPIX; p += 256) {
        const int i = p / NPIX, j = p - i*NPIX;
        const float dx = gbx[i]-gmx[j], dy = gby[i]-gmy[j];
        const float d2 = dx*dx + dy*dy;
        if (d2 < thrb2) { ++nnzb; sb += cosj[j]; }
        if (d2 < thrm2) { ++nnzm; sm += cosj[i]; }
    }
    for (int off = 32; off; off >>= 1) {
        sb += __shfl_down(sb,off); sm += __shfl_down(sm,off);
        nnzb += __shfl_down(nnzb,off); nnzm += __shfl_down(nnzm,off);
    }
    const int wid = tid >> 6;
    if ((tid & 63) == 0) {
        red[wid*4+0]=sb; red[wid*4+1]=sm; red[wid*4+2]=(float)nnzb; red[wid*4+3]=(float)nnzm;
    }
    __syncthreads();
    if (tid == 0) {
        float SB=0,SM=0,NB=0,NM=0;
        for (int w=0;w<4;++w){SB+=red[w*4+0];SM+=red[w*4+1];NB+=red[w*4+2];NM+=red[w*4+3];}
        const float lossb = (NB>0.f)?SB/NB:0.f, lossm = (NM>0.f)?SM/NM:0.f;
        const float cx1=xb+0.5f*wb, cx2=xm+0.5f*wm, cy1=yb+0.5f*hb, cy2=ym+0.5f*hm;
        const bool inter = (fabsf(cx1-cx2)*2.f < wb+wm) && (fabsf(cy1-cy2)*2.f < hb+hm);
        if (inter) { atomicAdd(&accum[0], -(lossb+lossm)); atomicAdd(&accum[1], 1.f); }
    }
}

__global__ void pixpro_mono_final(const float* __restrict__ accum,
                                  float* __restrict__ out)
{
    out[0] = accum[0] / fmaxf(accum[1], 1.0f);
}

// ============================= launch ======================================
extern "C" void kernel_launch(void* const* d_in, const int* in_sizes, int n_in,
                              void* d_out, int out_size, void* d_ws, size_t ws_size,
                              hipStream_t stream)
{
    const float* pbase = (const float*)d_in[2];
    const float* pmom  = (const float*)d_in[3];
    const int*   fbase = (const int*)d_in[4];
    const int*   fmom  = (const int*)d_in[5];
    float* out = (float*)d_out;

    const int B = in_sizes[2] / 4;   // p_base is (B,4)

    const size_t need = (size_t)B * 2 * (3 * NPIX) * sizeof(float)
                      + (size_t)B * 2 * sizeof(float);
    if (ws_size >= need) {
        const char* Ab = (const char*)d_in[0];
        const char* Bb = (const char*)d_in[1];
        float* partial = (float*)d_ws;
        float* perb    = partial + (size_t)B * 2 * (3 * NPIX);
        pixpro_reduce<<<B * 2, 256, 0, stream>>>(Ab, Bb, partial);
        pixpro_pairs<<<B, 64, 0, stream>>>(partial, pbase, pmom, fbase, fmom, perb);
        pixpro_final<<<1, 1024, 0, stream>>>(perb, out, B);
    } else {
        const float4* base4   = (const float4*)d_in[0];
        const float4* moment4 = (const float4*)d_in[1];
        float* accum = (float*)d_ws;  // 2 floats
        hipMemsetAsync(accum, 0, 2 * sizeof(float), stream);
        pixpro_mono<<<B, 256, 0, stream>>>(base4, moment4, pbase, pmom, fbase, fmom, accum);
        pixpro_mono_final<<<1, 1, 0, stream>>>(accum, out);
    }
}